// Round 10
// baseline (118.268 us; speedup 1.0000x reference)
//
#include <hip/hip_runtime.h>

#define N 10
#define D 1024
#define NREL 200
#define KCH 64            // k-slices in the gather (each KLEN rows)
#define KLEN 16           // D / KCH
#define MAXG 8            // max edges per gather group (register-blocked)

typedef float f32x4 __attribute__((ext_vector_type(4)));

// ---------------- workspace layout (float offsets) ----------------
// zeroed each call (by build_zero blocks 1..42): [q | k | root | x2acc | aggrel | agg]
#define OFF_Q       0                      // N*D
#define OFF_K       10240                  // N*D
#define OFF_ROOT    20480                  // N*D
#define OFF_X2ACC   30720                  // N*D
#define OFF_AGGREL  40960                  // D
#define OFF_AGG     41984                  // D
#define ZERO_FLOATS 43008                  // = 42 * 1024
#define OFF_OUT     43008                  // N*D   (plain-stored by e1)
#define OFF_WE      53248                  // 100 (pad 128)
#define OFF_NITEMS  53376                  // 1 int (pad 16)
#define OFF_ITEMS   53392                  // 100 items x 10 ints (pad -> 54400)
#define OFF_EMPART  54400                  // KCH*N*N*D floats (26.2 MB, overwritten)

// ---- block 0: build etype groups; blocks 1..42: zero the accumulator region ----
__global__ void build_zero(const int* __restrict__ speaker, int* __restrict__ n_items,
                           int* __restrict__ items, float* __restrict__ wsz) {
    if (blockIdx.x > 0) {
        int base = (blockIdx.x - 1) * 1024 + threadIdx.x * 4;
        f32x4 z = 0.f;
        *reinterpret_cast<f32x4*>(wsz + base) = z;
        return;
    }
    __shared__ int sp[N];
    __shared__ int gcnt[NREL];
    __shared__ int ibase[NREL];
    int tid = threadIdx.x;
    if (tid < N) sp[tid] = speaker[tid];
    __syncthreads();
    if (tid < NREL) {
        int c = 0;
        for (int e = 0; e < N * N; ++e) {
            int src = e / N, dst = e % N;
            int et = 2 * (sp[src] * N + sp[dst]) + (src >= dst ? 1 : 0);
            c += (et == tid);
        }
        gcnt[tid] = c;
    }
    __syncthreads();
    if (tid == 0) {
        int b = 0;
        for (int t = 0; t < NREL; ++t) { ibase[t] = b; b += (gcnt[t] + MAXG - 1) / MAXG; }
        *n_items = b;
    }
    __syncthreads();
    if (tid < NREL && gcnt[tid] > 0) {
        int it = ibase[tid], slot = 0;
        int* rec = items + it * 10;
        for (int e = 0; e < N * N; ++e) {
            int src = e / N, dst = e % N;
            int et = 2 * (sp[src] * N + sp[dst]) + (src >= dst ? 1 : 0);
            if (et != tid) continue;
            if (slot == 0) rec[0] = tid;
            rec[2 + slot] = e;
            if (++slot == MAXG) { rec[1] = MAXG; ++it; rec = items + it * 10; slot = 0; }
        }
        if (slot > 0) { rec[1] = slot; for (int g = slot; g < MAXG; ++g) rec[2 + g] = -1; }
    }
}

// ---- ONE dispatch: [bx<100] etype-grouped weight-gather -> em_part (plain stores,
//      compiler-scheduled unroll-4 loop); [bx>=100] q/k/root matvecs
__global__ void big_fused(const float* __restrict__ X, const float* __restrict__ Wrel,
                          const int* __restrict__ n_items, const int* __restrict__ items,
                          const float* __restrict__ Wq, const float* __restrict__ Wk,
                          const float* __restrict__ Wroot,
                          float* __restrict__ q, float* __restrict__ kout,
                          float* __restrict__ rootacc, float* __restrict__ em_part) {
    int bx = blockIdx.x, by = blockIdx.y, tid = threadIdx.x;
    if (bx < 100) {
        if (bx >= *n_items) return;        // block-uniform early exit (before any barrier)
        __shared__ int   meta[10];
        __shared__ float xs[MAXG][KLEN];
        if (tid < 10) meta[tid] = items[bx * 10 + tid];
        __syncthreads();
        int t = meta[0], gsize = meta[1];
        if (tid < MAXG * KLEN) {           // stage x slices (zero-padded for g>=gsize)
            int g = tid / KLEN, k = tid % KLEN;
            int e = meta[2 + g];
            xs[g][k] = (g < gsize) ? X[(e / N) * D + by * KLEN + k] : 0.f;
        }
        __syncthreads();
        int c0 = tid * 4;
        const float* W = Wrel + (size_t)t * D * D + (size_t)by * KLEN * D;
        f32x4 acc[MAXG];
#pragma unroll
        for (int g = 0; g < MAXG; ++g) acc[g] = 0.f;
#pragma unroll 4
        for (int k = 0; k < KLEN; ++k) {
            f32x4 w4 = *reinterpret_cast<const f32x4*>(W + (size_t)k * D + c0);
#pragma unroll
            for (int g = 0; g < MAXG; ++g) acc[g] += xs[g][k] * w4;
        }
        // plain stores: element (by, e, c) owned exclusively by this block
        for (int g = 0; g < gsize; ++g) {
            *reinterpret_cast<f32x4*>(
                em_part + ((size_t)(by * (N * N) + meta[2 + g])) * D + c0) = acc[g];
        }
    } else {
        int sel = bx - 100;                 // 0:Wq 1:Wk 2:Wroot
        int kb  = (by & 7) * 128;
        int c   = ((by >> 3) & 3) * 256 + tid;
        if (by >= 32) return;               // only 32 (kb,c) tiles used
        const float* W = (sel == 0) ? Wq : (sel == 1) ? Wk : Wroot;
        float*       Y = (sel == 0) ? q  : (sel == 1) ? kout : rootacc;
        __shared__ float xs2[N][128];
        for (int idx = tid; idx < N * 128; idx += 256) {
            int r = idx >> 7, k = idx & 127;
            xs2[r][k] = X[r * D + kb + k];
        }
        __syncthreads();
        float acc[N];
#pragma unroll
        for (int r = 0; r < N; ++r) acc[r] = 0.f;
#pragma unroll 4
        for (int k = 0; k < 128; ++k) {
            float w = W[(size_t)(kb + k) * D + c];
#pragma unroll
            for (int r = 0; r < N; ++r) acc[r] += xs2[r][k] * w;
        }
#pragma unroll
        for (int r = 0; r < N; ++r) atomicAdd(&Y[r * D + c], acc[r]);
    }
}

// ---- single block, 1024 threads: logits -> softmax -> (rel,dst)-mean -> w_e ----
// ALL __syncthreads() at top level (uniform).
__global__ void attn_edges(const float* __restrict__ q, const float* __restrict__ k,
                           const int* __restrict__ speaker, float* __restrict__ w_e) {
    __shared__ float logits[N * N];
    __shared__ float attn[N * N];
    __shared__ int   cnt[NREL * N];   // 8 KB
    int tid  = threadIdx.x;
    int wave = tid >> 6, lane = tid & 63;

    for (int p = wave; p < N * N; p += 16) {
        int i = p / N, j = p % N;
        const f32x4* qp = reinterpret_cast<const f32x4*>(q + i * D);
        const f32x4* kp = reinterpret_cast<const f32x4*>(k + j * D);
        float acc = 0.f;
#pragma unroll
        for (int it = 0; it < 4; ++it) {
            f32x4 qa = qp[lane + it * 64];
            f32x4 ka = kp[lane + it * 64];
            acc += qa.x * ka.x + qa.y * ka.y + qa.z * ka.z + qa.w * ka.w;
        }
        for (int off = 32; off; off >>= 1) acc += __shfl_down(acc, off);
        if (lane == 0) logits[p] = acc * (1.0f / 32.0f);   // 1/sqrt(1024)
    }
    __syncthreads();

    if (tid < N) {                        // row softmax
        float m = -1e30f;
        for (int j = 0; j < N; ++j) m = fmaxf(m, logits[tid * N + j]);
        float s = 0.f, e[N];
        for (int j = 0; j < N; ++j) { e[j] = expf(logits[tid * N + j] - m); s += e[j]; }
        for (int j = 0; j < N; ++j) attn[tid * N + j] = e[j] / s;
    }
    for (int i = tid; i < NREL * N; i += 1024) cnt[i] = 0;
    __syncthreads();          // attn visible + cnt zeroed

    int et = 0;
    if (tid < N * N) {
        int src = tid / N, dst = tid % N;
        et = 2 * (speaker[src] * N + speaker[dst]) + (src >= dst ? 1 : 0);
        atomicAdd(&cnt[et * N + dst], 1);
    }
    __syncthreads();          // counts complete (uniform barrier)

    if (tid < N * N) {
        w_e[tid] = attn[tid] / (float)cnt[et * N + (tid % N)];
    }
}

// ---- e1: out[dst] = sum_src w_e * (sum_by em_part) + root + bias ; agg += out;
//      also dout right half (X copy). grid (10 dst, 8 jtiles), block 256.
__global__ void e1_out(const float* __restrict__ em_part, const float* __restrict__ w_e,
                       const float* __restrict__ rootacc, const float* __restrict__ bias,
                       const float* __restrict__ X,
                       float* __restrict__ out, float* __restrict__ agg,
                       float* __restrict__ dout) {
    __shared__ float wes[N * N];
    __shared__ float red[8][128];
    int dst = blockIdx.x, jt = blockIdx.y;
    int tid = threadIdx.x;
    int lane32 = tid & 31, g = tid >> 5;   // 8 row-groups x 32 lanes
    int jbase = jt * 128;
    if (tid < N * N) wes[tid] = w_e[tid];
    __syncthreads();
    f32x4 s = 0.f;
    for (int p = 0; p < 80; ++p) {         // 640 (by,src) pairs / 8 groups
        int idx = p * 8 + g;
        int by = idx / 10, src = idx % 10;
        f32x4 v = *reinterpret_cast<const f32x4*>(
            em_part + ((size_t)(by * (N * N) + src * N + dst)) * D + jbase + lane32 * 4);
        s += wes[src * N + dst] * v;
    }
    *reinterpret_cast<f32x4*>(&red[g][lane32 * 4]) = s;
    __syncthreads();
    if (tid < 128) {
        float t = 0.f;
#pragma unroll
        for (int gg = 0; gg < 8; ++gg) t += red[gg][tid];
        int j = jbase + tid;
        float o = t + rootacc[dst * D + j] + bias[j];
        out[dst * D + j] = o;
        atomicAdd(&agg[j], o);
        dout[dst * 2 * D + D + j] = X[dst * D + j];   // concat right half
    }
}

// ---- e2: x2acc = out @ gcn_root_w (w=0) ; aggrel = agg @ gcn_rel_w (w=1)
//      grid (32 k-slices, 2), block 256; each W matrix read exactly once.
__global__ void e2_matvec(const float* __restrict__ out, const float* __restrict__ agg,
                          const float* __restrict__ root_w, const float* __restrict__ rel_w,
                          float* __restrict__ x2acc, float* __restrict__ aggrel) {
    __shared__ float xs[N][32];
    int kb  = blockIdx.x * 32;
    int w   = blockIdx.y;
    int tid = threadIdx.x;
    int c0  = tid * 4;
    if (w == 0) {
        for (int i = tid; i < N * 32; i += 256)
            xs[i >> 5][i & 31] = out[(i >> 5) * D + kb + (i & 31)];
        __syncthreads();
        f32x4 acc[N];
#pragma unroll
        for (int r = 0; r < N; ++r) acc[r] = 0.f;
#pragma unroll 8
        for (int k = 0; k < 32; ++k) {
            f32x4 w4 = *reinterpret_cast<const f32x4*>(root_w + (size_t)(kb + k) * D + c0);
#pragma unroll
            for (int r = 0; r < N; ++r) acc[r] += xs[r][k] * w4;
        }
#pragma unroll
        for (int r = 0; r < N; ++r) {
            float* y = x2acc + r * D + c0;
            atomicAdd(y + 0, acc[r].x); atomicAdd(y + 1, acc[r].y);
            atomicAdd(y + 2, acc[r].z); atomicAdd(y + 3, acc[r].w);
        }
    } else {
        if (tid < 32) xs[0][tid] = agg[kb + tid];
        __syncthreads();
        f32x4 acc = 0.f;
#pragma unroll 8
        for (int k = 0; k < 32; ++k) {
            f32x4 w4 = *reinterpret_cast<const f32x4*>(rel_w + (size_t)(kb + k) * D + c0);
            acc += xs[0][k] * w4;
        }
        float* y = aggrel + c0;
        atomicAdd(y + 0, acc.x); atomicAdd(y + 1, acc.y);
        atomicAdd(y + 2, acc.z); atomicAdd(y + 3, acc.w);
    }
}

// ---- e3: dout left half = x2acc + aggrel + rel_b ; grid (10, 4), block 256 ----
__global__ void e3_concat(const float* __restrict__ x2acc, const float* __restrict__ aggrel,
                          const float* __restrict__ rel_b, float* __restrict__ dout) {
    int r = blockIdx.x, c = blockIdx.y * 256 + threadIdx.x;
    dout[r * 2 * D + c] = x2acc[r * D + c] + aggrel[c] + rel_b[c];
}

extern "C" void kernel_launch(void* const* d_in, const int* in_sizes, int n_in,
                              void* d_out, int out_size, void* d_ws, size_t ws_size,
                              hipStream_t stream) {
    const float* X          = (const float*)d_in[0];
    const int*   speaker    = (const int*)  d_in[1];
    const float* Wq         = (const float*)d_in[2];
    const float* Wk         = (const float*)d_in[3];
    const float* Wrel       = (const float*)d_in[4];
    const float* Wroot      = (const float*)d_in[5];
    const float* bias       = (const float*)d_in[6];
    const float* gcn_rel_w  = (const float*)d_in[7];
    const float* gcn_rel_b  = (const float*)d_in[8];
    const float* gcn_root_w = (const float*)d_in[9];
    float* ws   = (float*)d_ws;
    float* dout = (float*)d_out;

    float* q       = ws + OFF_Q;
    float* kbuf    = ws + OFF_K;
    float* rootacc = ws + OFF_ROOT;
    float* x2acc   = ws + OFF_X2ACC;
    float* aggrel  = ws + OFF_AGGREL;
    float* agg     = ws + OFF_AGG;
    float* out     = ws + OFF_OUT;
    float* w_e     = ws + OFF_WE;
    int*   nitems  = (int*)(ws + OFF_NITEMS);
    int*   items   = (int*)(ws + OFF_ITEMS);
    float* em_part = ws + OFF_EMPART;

    dim3 blk(256);
    // groups + zeroing fused (no separate memset node)
    build_zero<<<dim3(43), blk, 0, stream>>>(speaker, nitems, items, ws);

    // gather (dedup'd, ~n_items*4MB, KCH=64 k-slices) + q/k/root matvecs
    big_fused<<<dim3(103, KCH), blk, 0, stream>>>(X, Wrel, nitems, items, Wq, Wk, Wroot,
                                                  q, kbuf, rootacc, em_part);

    attn_edges<<<1, dim3(1024), 0, stream>>>(q, kbuf, speaker, w_e);
    e1_out<<<dim3(N, 8), blk, 0, stream>>>(em_part, w_e, rootacc, bias, X, out, agg, dout);
    e2_matvec<<<dim3(32, 2), blk, 0, stream>>>(out, agg, gcn_root_w, gcn_rel_w, x2acc, aggrel);
    e3_concat<<<dim3(N, 4), blk, 0, stream>>>(x2acc, aggrel, gcn_rel_b, dout);
}

// Round 11
// 105.064 us; speedup vs baseline: 1.1257x; 1.1257x over previous
//
#include <hip/hip_runtime.h>

#define N 10
#define D 1024
#define NREL 200
#define KCH 32            // k-slices in the gather (each KLEN rows)
#define KLEN 32           // D / KCH
#define MAXG 8            // max edges per gather group (register-blocked)

typedef float f32x4 __attribute__((ext_vector_type(4)));

// ---------------- workspace layout (float offsets) ----------------
// zeroed each call (build_zero blocks 1..41): [q | k | root | x2acc | aggrel]
#define OFF_Q       0                      // N*D
#define OFF_K       (OFF_Q + N*D)          // N*D
#define OFF_ROOT    (OFF_K + N*D)          // N*D
#define OFF_X2ACC   (OFF_ROOT + N*D)       // N*D
#define OFF_AGGREL  (OFF_X2ACC + N*D)      // D
#define ZERO_FLOATS (OFF_AGGREL + D)       // 41984 = 41 * 1024
#define OFF_EM      ZERO_FLOATS            // N*N*D   (fully overwritten by reduce part)
#define OFF_WE      (OFF_EM + N*N*D)       // 100 (pad 128)
#define OFF_NITEMS  (OFF_WE + 128)         // 1 int (pad 16)
#define OFF_ITEMS   (OFF_NITEMS + 16)      // 100 items x 10 ints
#define OFF_EMPART  (OFF_ITEMS + 1024)     // KCH*N*N*D floats (13.1 MB, overwritten)

// ---- block 0: build etype groups; blocks 1..41: zero the accumulator region ----
__global__ void build_zero(const int* __restrict__ speaker, int* __restrict__ n_items,
                           int* __restrict__ items, float* __restrict__ wsz) {
    if (blockIdx.x > 0) {
        int base = (blockIdx.x - 1) * 1024 + threadIdx.x * 4;
        f32x4 z = 0.f;
        *reinterpret_cast<f32x4*>(wsz + base) = z;
        return;
    }
    __shared__ int sp[N];
    __shared__ int gcnt[NREL];
    __shared__ int ibase[NREL];
    int tid = threadIdx.x;
    if (tid < N) sp[tid] = speaker[tid];
    __syncthreads();
    if (tid < NREL) {
        int c = 0;
        for (int e = 0; e < N * N; ++e) {
            int src = e / N, dst = e % N;
            int et = 2 * (sp[src] * N + sp[dst]) + (src >= dst ? 1 : 0);
            c += (et == tid);
        }
        gcnt[tid] = c;
    }
    __syncthreads();
    if (tid == 0) {
        int b = 0;
        for (int t = 0; t < NREL; ++t) { ibase[t] = b; b += (gcnt[t] + MAXG - 1) / MAXG; }
        *n_items = b;
    }
    __syncthreads();
    if (tid < NREL && gcnt[tid] > 0) {
        int it = ibase[tid], slot = 0;
        int* rec = items + it * 10;
        for (int e = 0; e < N * N; ++e) {
            int src = e / N, dst = e % N;
            int et = 2 * (sp[src] * N + sp[dst]) + (src >= dst ? 1 : 0);
            if (et != tid) continue;
            if (slot == 0) rec[0] = tid;
            rec[2 + slot] = e;
            if (++slot == MAXG) { rec[1] = MAXG; ++it; rec = items + it * 10; slot = 0; }
        }
        if (slot > 0) { rec[1] = slot; for (int g = slot; g < MAXG; ++g) rec[2 + g] = -1; }
    }
}

// ---- R7-exact: [bx<100] etype-grouped weight-gather -> em_part (plain stores,
//      compiler-scheduled unroll-4); [bx>=100] q/k/root pre-matvecs
__global__ void big_fused(const float* __restrict__ X, const float* __restrict__ Wrel,
                          const int* __restrict__ n_items, const int* __restrict__ items,
                          const float* __restrict__ Wq, const float* __restrict__ Wk,
                          const float* __restrict__ Wroot,
                          float* __restrict__ q, float* __restrict__ kout,
                          float* __restrict__ rootacc, float* __restrict__ em_part) {
    int bx = blockIdx.x, by = blockIdx.y, tid = threadIdx.x;
    if (bx < 100) {
        if (bx >= *n_items) return;        // block-uniform early exit (before any barrier)
        __shared__ int   meta[10];
        __shared__ float xs[MAXG][KLEN];
        if (tid < 10) meta[tid] = items[bx * 10 + tid];
        __syncthreads();
        int t = meta[0], gsize = meta[1];
        {   // stage x slices (zero-padded for g>=gsize so the unrolled FMAs are inert)
            int g = tid >> 5, k = tid & 31;            // 256 threads == MAXG*KLEN
            int e = meta[2 + g];
            xs[g][k] = (g < gsize) ? X[(e / N) * D + by * KLEN + k] : 0.f;
        }
        __syncthreads();
        int c0 = tid * 4;
        const float* W = Wrel + (size_t)t * D * D + (size_t)by * KLEN * D;
        f32x4 acc[MAXG];
#pragma unroll
        for (int g = 0; g < MAXG; ++g) acc[g] = 0.f;
#pragma unroll 4
        for (int k = 0; k < KLEN; ++k) {
            f32x4 w4 = *reinterpret_cast<const f32x4*>(W + (size_t)k * D + c0);
#pragma unroll
            for (int g = 0; g < MAXG; ++g) acc[g] += xs[g][k] * w4;
        }
        for (int g = 0; g < gsize; ++g) {
            *reinterpret_cast<f32x4*>(
                em_part + ((size_t)(by * (N * N) + meta[2 + g])) * D + c0) = acc[g];
        }
    } else {
        int sel = bx - 100;                 // 0:Wq 1:Wk 2:Wroot
        int kb  = (by & 7) * 128;
        int c   = (by >> 3) * 256 + tid;
        const float* W = (sel == 0) ? Wq : (sel == 1) ? Wk : Wroot;
        float*       Y = (sel == 0) ? q  : (sel == 1) ? kout : rootacc;
        __shared__ float xs2[N][128];
        for (int idx = tid; idx < N * 128; idx += 256) {
            int r = idx >> 7, k = idx & 127;
            xs2[r][k] = X[r * D + kb + k];
        }
        __syncthreads();
        float acc[N];
#pragma unroll
        for (int r = 0; r < N; ++r) acc[r] = 0.f;
#pragma unroll 4
        for (int k = 0; k < 128; ++k) {
            float w = W[(size_t)(kb + k) * D + c];
#pragma unroll
            for (int r = 0; r < N; ++r) acc[r] += xs2[r][k] * w;
        }
#pragma unroll
        for (int r = 0; r < N; ++r) atomicAdd(&Y[r * D + c], acc[r]);
    }
}

// ---- merged dispatch, 512 threads: blocks 0..799 reduce em_part -> em;
//      block 800 computes attn -> w_e. All barriers block-uniform.
__global__ void attn_reduce(const float* __restrict__ q, const float* __restrict__ k,
                            const int* __restrict__ speaker,
                            const float* __restrict__ em_part,
                            float* __restrict__ w_e, float* __restrict__ em) {
    int bx  = blockIdx.x;
    int tid = threadIdx.x;
    if (bx < 800) {
        // em[e][jt*128 + col] = sum_{by<32} em_part[by][e][...]
        __shared__ float ps[4][128];
        int e = bx >> 3, jt = bx & 7;
        int col = tid & 127, h = tid >> 7;      // 4 by-quarters x 128 cols
        int jbase = jt * 128;
        float s = 0.f;
#pragma unroll
        for (int i = 0; i < 8; ++i) {
            int by = h * 8 + i;
            s += em_part[((size_t)(by * (N * N) + e)) * D + jbase + col];
        }
        ps[h][col] = s;
        __syncthreads();
        if (tid < 128)
            em[(size_t)e * D + jbase + tid] = ps[0][tid] + ps[1][tid] + ps[2][tid] + ps[3][tid];
        return;
    }
    // ---- attention block (512 threads = 8 waves) ----
    __shared__ float logits[N * N];
    __shared__ float attn[N * N];
    __shared__ int   cnt[NREL * N];   // 8 KB
    int wave = tid >> 6, lane = tid & 63;

    for (int p = wave; p < N * N; p += 8) {
        int i = p / N, j = p % N;
        const f32x4* qp = reinterpret_cast<const f32x4*>(q + i * D);
        const f32x4* kp = reinterpret_cast<const f32x4*>(k + j * D);
        float acc = 0.f;
#pragma unroll
        for (int it = 0; it < 4; ++it) {
            f32x4 qa = qp[lane + it * 64];
            f32x4 ka = kp[lane + it * 64];
            acc += qa.x * ka.x + qa.y * ka.y + qa.z * ka.z + qa.w * ka.w;
        }
        for (int off = 32; off; off >>= 1) acc += __shfl_down(acc, off);
        if (lane == 0) logits[p] = acc * (1.0f / 32.0f);   // 1/sqrt(1024)
    }
    __syncthreads();

    if (tid < N) {                        // row softmax
        float m = -1e30f;
        for (int j = 0; j < N; ++j) m = fmaxf(m, logits[tid * N + j]);
        float s = 0.f, e[N];
        for (int j = 0; j < N; ++j) { e[j] = expf(logits[tid * N + j] - m); s += e[j]; }
        for (int j = 0; j < N; ++j) attn[tid * N + j] = e[j] / s;
    }
    for (int i = tid; i < NREL * N; i += 512) cnt[i] = 0;
    __syncthreads();          // attn visible + cnt zeroed

    int et = 0;
    if (tid < N * N) {
        int src = tid / N, dst = tid % N;
        et = 2 * (speaker[src] * N + speaker[dst]) + (src >= dst ? 1 : 0);
        atomicAdd(&cnt[et * N + dst], 1);
    }
    __syncthreads();          // counts complete (uniform barrier)

    if (tid < N * N) {
        w_e[tid] = attn[tid] / (float)cnt[et * N + (tid % N)];
    }
}

// ---- R7-exact: combine em*w_e + root + bias on the fly, then second-layer matvec ----
// rows 0..9: x2acc[r] += out[r] @ gcn_root_w ; row 10: aggrel += (sum_r out[r]) @ gcn_rel_w
// grid (11, 4, 8), block 256
__global__ void combine_final(const float* __restrict__ em, const float* __restrict__ w_e,
                              const float* __restrict__ rootacc, const float* __restrict__ bias,
                              const float* __restrict__ root_w, const float* __restrict__ rel_w,
                              float* __restrict__ x2acc, float* __restrict__ aggrel) {
    __shared__ float wes[N * N];
    __shared__ float xs[128];
    int r   = blockIdx.x;
    int tid = threadIdx.x;
    int c   = blockIdx.y * 256 + tid;
    int kb  = blockIdx.z * 128;
    if (tid < N * N) wes[tid] = w_e[tid];
    __syncthreads();
    if (tid < 128) {
        int j = kb + tid;
        float v;
        if (r < N) {
            v = rootacc[r * D + j] + bias[j];
#pragma unroll
            for (int src = 0; src < N; ++src) {
                int e = src * N + r;
                v += wes[e] * em[(size_t)e * D + j];
            }
        } else {
            v = (float)N * bias[j];
#pragma unroll
            for (int rr = 0; rr < N; ++rr) v += rootacc[rr * D + j];
            for (int e = 0; e < N * N; ++e) v += wes[e] * em[(size_t)e * D + j];
        }
        xs[tid] = v;
    }
    __syncthreads();
    const float* W = (r < N) ? root_w : rel_w;
    float*       y = (r < N) ? x2acc + r * D : aggrel;
    const float* Wp = W + (size_t)kb * D + c;
    float acc = 0.f;
#pragma unroll 8
    for (int k = 0; k < 128; ++k) acc += xs[k] * Wp[(size_t)k * D];
    atomicAdd(&y[c], acc);
}

// ---- R7-exact: dout[r][0:1024] = x2acc + aggrel + rel_b ; dout[r][1024:2048] = X[r] ----
// grid (10, 8), block 256
__global__ void final_concat(const float* __restrict__ x2acc, const float* __restrict__ aggrel,
                             const float* __restrict__ rel_b, const float* __restrict__ X,
                             float* __restrict__ dout) {
    int r = blockIdx.x, c = blockIdx.y * 256 + threadIdx.x;
    if (c < D) dout[r * 2 * D + c] = x2acc[r * D + c] + aggrel[c] + rel_b[c];
    else       dout[r * 2 * D + c] = X[r * D + (c - D)];
}

extern "C" void kernel_launch(void* const* d_in, const int* in_sizes, int n_in,
                              void* d_out, int out_size, void* d_ws, size_t ws_size,
                              hipStream_t stream) {
    const float* X          = (const float*)d_in[0];
    const int*   speaker    = (const int*)  d_in[1];
    const float* Wq         = (const float*)d_in[2];
    const float* Wk         = (const float*)d_in[3];
    const float* Wrel       = (const float*)d_in[4];
    const float* Wroot      = (const float*)d_in[5];
    const float* bias       = (const float*)d_in[6];
    const float* gcn_rel_w  = (const float*)d_in[7];
    const float* gcn_rel_b  = (const float*)d_in[8];
    const float* gcn_root_w = (const float*)d_in[9];
    float* ws   = (float*)d_ws;
    float* dout = (float*)d_out;

    float* q       = ws + OFF_Q;
    float* kbuf    = ws + OFF_K;
    float* rootacc = ws + OFF_ROOT;
    float* x2acc   = ws + OFF_X2ACC;
    float* aggrel  = ws + OFF_AGGREL;
    float* em      = ws + OFF_EM;
    float* w_e     = ws + OFF_WE;
    int*   nitems  = (int*)(ws + OFF_NITEMS);
    int*   items   = (int*)(ws + OFF_ITEMS);
    float* em_part = ws + OFF_EMPART;

    dim3 blk(256);
    // groups + accumulator zeroing in one dispatch
    build_zero<<<dim3(42), blk, 0, stream>>>(speaker, nitems, items, ws);

    // gather (dedup'd, ~n_items*4MB) + q/k/root matvecs — R7-exact
    big_fused<<<dim3(103, KCH), blk, 0, stream>>>(X, Wrel, nitems, items, Wq, Wk, Wroot,
                                                  q, kbuf, rootacc, em_part);

    // attention (1 block) + em_part reduction (800 blocks) in one dispatch
    attn_reduce<<<dim3(801), dim3(512), 0, stream>>>(q, kbuf, speaker, em_part, w_e, em);

    combine_final<<<dim3(N + 1, 4, 8), blk, 0, stream>>>(em, w_e, rootacc, bias,
                                                         gcn_root_w, gcn_rel_w, x2acc, aggrel);
    final_concat<<<dim3(N, 8), blk, 0, stream>>>(x2acc, aggrel, gcn_rel_b, X, dout);
}